// Round 2
// baseline (775.468 us; speedup 1.0000x reference)
//
#include <hip/hip_runtime.h>

// Monte-Carlo (stochastic) 2x2 pooling.
// Reference: per 2x2 block, idx = argmax_k( log(max(x_k,EPS)) + gumbel(u_k) ),
//            gumbel(u) = -log(-log(clip(u, EPS, 1-EPS))).
// Monotone-transform equivalence: argmax of log(x'_k) - log(w_k) with
// w_k = -log(clip(u_k)) > 0  ==  argmax of x'_k / w_k, resolved via
// cross-multiplication (preserves argmax's first-index tie-break with a
// strict '>' ascending scan).
//
// Decision runs in f32 (logf + f32 products); falls back to the exact double
// path ONLY when a comparison is within a conservative relative margin (2e-6).
// f32 error budget: logf <= ~2.4e-7 rel, clip-const diff <= ~6e-8, product
// rounding <= ~1.2e-7 -> <= ~4.4e-7 per side << 2e-6 margin. Ambiguous cases
// (expected O(tens) of 25.7M) rerun the double code, bit-identical to the
// originally-passing kernel.
//
// This version processes TWO horizontally-adjacent outputs per thread:
//   - x loads become perfect float4 (16 B/lane, consecutive across lanes)
//   - u loads are two float4s (stride-2 across lanes; complementary halves of
//     the same cache lines -> full line utilization)
//   - out stores become float2
//   - index div/mod chain paid once per 2 outputs
//
// Shapes: x (32,64,224,224) f32, u (32,64,112,112,4) f32, out (32,64,112,112) f32.

#define PH 112
#define PW 112
#define PPW 56          // output-pairs per pooled row
#define EPS 1e-12

__device__ __forceinline__ float decide(float x0, float x1, float x2, float x3,
                                        float4 uu) {
    // ---------------- fast path: all-f32 ----------------
    // u < 1.0 always (uniform [0,1) f32 max is 1-2^-24) -> upper clip inactive.
    float xf[4] = { fmaxf(x0, 1e-12f), fmaxf(x1, 1e-12f),
                    fmaxf(x2, 1e-12f), fmaxf(x3, 1e-12f) };
    float uf[4] = { uu.x, uu.y, uu.z, uu.w };
    float wf[4];
#pragma unroll
    for (int k = 0; k < 4; ++k) {
        float uc = fmaxf(uf[k], 1e-12f);
        wf[k] = -logf(uc);    // > 0 since uc < 1
    }

    int best = 0;
    bool unsure = false;
#pragma unroll
    for (int k = 1; k < 4; ++k) {
        float a = xf[k] * wf[best];
        float b = xf[best] * wf[k];
        // products strictly positive; relative-margin ambiguity test
        if (fabsf(a - b) <= 2e-6f * fmaxf(a, b)) unsure = true;
        if (a > b) best = k;
    }

    // ------------- exact fallback: double (rare) -------------
    if (__builtin_expect(unsure, 0)) {
        double xv[4] = { fmax((double)x0, EPS), fmax((double)x1, EPS),
                         fmax((double)x2, EPS), fmax((double)x3, EPS) };
        double w[4];
#pragma unroll
        for (int k = 0; k < 4; ++k) {
            double uc = fmin(fmax((double)uf[k], EPS), 1.0 - EPS);
            w[k] = -log(uc);
        }
        best = 0;
#pragma unroll
        for (int k = 1; k < 4; ++k) {
            if (xv[k] * w[best] > xv[best] * w[k]) best = k;
        }
    }

    return (float)best;
}

__global__ __launch_bounds__(256) void mc_pool_kernel(const float* __restrict__ x,
                                                      const float* __restrict__ u,
                                                      float* __restrict__ out,
                                                      int n_pair) {
    int o2 = blockIdx.x * blockDim.x + threadIdx.x;
    if (o2 >= n_pair) return;

    int jp = o2 % PPW;        // pair index within pooled row (covers cols 2jp, 2jp+1)
    int t  = o2 / PPW;
    int i  = t % PH;          // pooled row
    int bc = t / PH;          // fused batch*channel

    // x as float4: each (b,c) image is 224*224 floats = 12544 float4;
    // input row 2i holds 56 float4; float4 #jp covers x[2i][4jp .. 4jp+3],
    // i.e. the top halves of output blocks (i, 2jp) and (i, 2jp+1).
    const float4* __restrict__ x4 = (const float4*)x;
    long rbase = (long)bc * 12544 + (long)i * 112 + jp;
    float4 ra = x4[rbase];        // row 2i
    float4 rb = x4[rbase + 56];   // row 2i+1

    // u: 4 contiguous floats per output; outputs 2*o2 and 2*o2+1.
    const float4* __restrict__ u4p = (const float4*)u;
    long o = (long)o2 * 2;
    float4 u0 = u4p[o];
    float4 u1 = u4p[o + 1];

    float2 res;
    res.x = decide(ra.x, ra.y, rb.x, rb.y, u0);   // output (i, 2jp)
    res.y = decide(ra.z, ra.w, rb.z, rb.w, u1);   // output (i, 2jp+1)

    ((float2*)out)[o2] = res;
}

extern "C" void kernel_launch(void* const* d_in, const int* in_sizes, int n_in,
                              void* d_out, int out_size, void* d_ws, size_t ws_size,
                              hipStream_t stream) {
    const float* x = (const float*)d_in[0];
    const float* u = (const float*)d_in[1];
    float* out = (float*)d_out;
    int n_pair = out_size / 2;  // 32*64*112*112 / 2 = 12,845,056
    int block = 256;
    int grid = (n_pair + block - 1) / block;
    mc_pool_kernel<<<grid, block, 0, stream>>>(x, u, out, n_pair);
}